// Round 1
// baseline (261.233 us; speedup 1.0000x reference)
//
#include <hip/hip_runtime.h>
#include <cstdint>
#include <cstddef>

#define N_SEQ 4096
#define D_HEAD 128
#define KP_DIM 256

typedef __attribute__((ext_vector_type(4))) float f32x4;
typedef __attribute__((ext_vector_type(8))) short bf16x8;
typedef __attribute__((ext_vector_type(4))) short s16x4;

static __device__ __forceinline__ short f2bf(float f) {
  uint32_t u = __builtin_bit_cast(uint32_t, f);
  u += 0x7FFFu + ((u >> 16) & 1u);
  return (short)(u >> 16);
}

static __device__ __forceinline__ int swz8(int r) { return (r ^ (r >> 2)) & 7; }

// ---------------------------------------------------------------------------
// Stage 1: partial projections.  grid (4 n-chunks, 2 proj, 32 batch), 512 thr.
// Computes pws[b][p][s][k(256)][d(128)] = sum_{n in chunk s} W[k,n] * X[b,n,d]
// ---------------------------------------------------------------------------
__global__ __launch_bounds__(512) void proj_partial_kernel(
    const float* __restrict__ Kin, const float* __restrict__ Vin,
    const float* __restrict__ EW, const float* __restrict__ FW,
    float* __restrict__ pws) {
  const int s = blockIdx.x;
  const int p = blockIdx.y;
  const int b = blockIdx.z;
  const float* __restrict__ X = (p == 0 ? Kin : Vin) + (size_t)b * (N_SEQ * D_HEAD);
  const float* __restrict__ W = (p == 0 ? EW : FW);
  float* __restrict__ outp = pws + ((((size_t)b * 2 + p) * 4) + s) * (KP_DIM * D_HEAD);

  __shared__ __align__(16) short lw[KP_DIM * 64];  // W tile [256][64] bf16, swizzled
  __shared__ __align__(16) short xt[D_HEAD * 64];  // X^T tile [128][64] bf16, swizzled

  const int t = threadIdx.x;
  const int lane = t & 63;
  const int w = t >> 6;
  const int wm = (w >> 1) * 64;   // k-row offset of this wave
  const int wn = (w & 1) * 64;    // d offset of this wave
  const int l15 = lane & 15;
  const int l4 = lane >> 4;

  f32x4 acc[4][4];
#pragma unroll
  for (int i = 0; i < 4; ++i)
#pragma unroll
    for (int j = 0; j < 4; ++j) acc[i][j] = (f32x4){0.f, 0.f, 0.f, 0.f};

  const int n0 = s * 1024;
  const int dq = t & 31;   // d-quad for X staging
  const int nq = t >> 5;   // n-quad for X staging (0..15)

  for (int nb = 0; nb < 1024; nb += 64) {
    const int nc = n0 + nb;
    // --- stage W tile [256 k][64 n] ---
#pragma unroll
    for (int it = 0; it < 8; ++it) {
      int id = t + it * 512;
      int kr = id >> 4, f4 = id & 15;
      f32x4 wv = *(const f32x4*)(W + (size_t)kr * N_SEQ + nc + f4 * 4);
      s16x4 h = {f2bf(wv[0]), f2bf(wv[1]), f2bf(wv[2]), f2bf(wv[3])};
      *(s16x4*)(&lw[kr * 64 + ((f4 * 4) ^ (swz8(kr) << 3))]) = h;
    }
    // --- stage X^T tile [128 d][64 n] ---
    {
      f32x4 x0 = *(const f32x4*)(X + (size_t)(nc + nq * 4 + 0) * D_HEAD + dq * 4);
      f32x4 x1 = *(const f32x4*)(X + (size_t)(nc + nq * 4 + 1) * D_HEAD + dq * 4);
      f32x4 x2 = *(const f32x4*)(X + (size_t)(nc + nq * 4 + 2) * D_HEAD + dq * 4);
      f32x4 x3 = *(const f32x4*)(X + (size_t)(nc + nq * 4 + 3) * D_HEAD + dq * 4);
#pragma unroll
      for (int i = 0; i < 4; ++i) {
        int row = dq * 4 + i;  // d index
        s16x4 h = {f2bf(x0[i]), f2bf(x1[i]), f2bf(x2[i]), f2bf(x3[i])};
        *(s16x4*)(&xt[row * 64 + ((nq * 4) ^ (swz8(row) << 3))]) = h;
      }
    }
    __syncthreads();
    // --- compute: 2 K-steps of 32 ---
#pragma unroll
    for (int ks2 = 0; ks2 < 2; ++ks2) {
      const int col0 = ks2 * 32 + l4 * 8;
      bf16x8 a[4], bb[4];
#pragma unroll
      for (int mt = 0; mt < 4; ++mt) {
        int row = wm + mt * 16 + l15;
        a[mt] = *(const bf16x8*)(&lw[row * 64 + (col0 ^ (swz8(row) << 3))]);
      }
#pragma unroll
      for (int nt = 0; nt < 4; ++nt) {
        int row = wn + nt * 16 + l15;
        bb[nt] = *(const bf16x8*)(&xt[row * 64 + (col0 ^ (swz8(row) << 3))]);
      }
#pragma unroll
      for (int mt = 0; mt < 4; ++mt)
#pragma unroll
        for (int nt = 0; nt < 4; ++nt)
          acc[mt][nt] = __builtin_amdgcn_mfma_f32_16x16x32_bf16(a[mt], bb[nt], acc[mt][nt], 0, 0, 0);
    }
    __syncthreads();
  }
  // --- write partials f32 ---
#pragma unroll
  for (int mt = 0; mt < 4; ++mt)
#pragma unroll
    for (int nt = 0; nt < 4; ++nt)
#pragma unroll
      for (int r = 0; r < 4; ++r) {
        int kk = wm + mt * 16 + l4 * 4 + r;
        int dd = wn + nt * 16 + l15;
        outp[kk * D_HEAD + dd] = acc[mt][nt][r];
      }
}

// ---------------------------------------------------------------------------
// Stage 1b: reduce 4 partials + bias -> kp[b][k][d] bf16, vpt[b][d][k] bf16
// grid 64 (b*2+p), 256 thr
// ---------------------------------------------------------------------------
__global__ __launch_bounds__(256) void reduce_bias_kernel(
    const float* __restrict__ pws, const float* __restrict__ Eb,
    const float* __restrict__ Fb, short* __restrict__ kp, short* __restrict__ vpt) {
  const int p = blockIdx.x & 1;
  const int b = blockIdx.x >> 1;
  const float* __restrict__ base = pws + (((size_t)b * 2 + p) * 4) * (KP_DIM * D_HEAD);
  const float* __restrict__ bias = (p == 0) ? Eb : Fb;
  const int t = threadIdx.x;
  __shared__ short tile[KP_DIM * D_HEAD];  // 64KB, used by p==1 only
  if (p == 0) {
    for (int i = t; i < KP_DIM * D_HEAD; i += 256) {
      int k = i >> 7;
      float v = base[i] + base[i + 32768] + base[i + 65536] + base[i + 98304] + bias[k];
      kp[(size_t)b * (KP_DIM * D_HEAD) + i] = f2bf(v);
    }
  } else {
    for (int i = t; i < KP_DIM * D_HEAD; i += 256) {
      int k = i >> 7, d = i & 127;
      float v = base[i] + base[i + 32768] + base[i + 65536] + base[i + 98304] + bias[k];
      tile[k * D_HEAD + (d ^ ((k & 15) << 3))] = f2bf(v);
    }
    __syncthreads();
    for (int i = t; i < KP_DIM * D_HEAD; i += 256) {
      int d = i >> 8, k = i & 255;
      vpt[(size_t)b * (KP_DIM * D_HEAD) + i] = tile[k * D_HEAD + (d ^ ((k & 15) << 3))];
    }
  }
}

// ---------------------------------------------------------------------------
// Stage 2: scores = Q @ KP^T * scale; softmax over k; out = P @ VP
// grid (64 row-tiles, 32 b), 256 thr (4 waves x 16 rows)
// ---------------------------------------------------------------------------
__global__ __launch_bounds__(256) void attn_kernel(
    const float* __restrict__ Q, const short* __restrict__ kp,
    const short* __restrict__ vpt, float* __restrict__ out) {
  const int tileI = blockIdx.x;
  const int b = blockIdx.y;
  const int n0 = tileI * 64;
  const int t = threadIdx.x;
  const int lane = t & 63;
  const int w = t >> 6;
  const int l15 = lane & 15, l4 = lane >> 4;

  __shared__ __align__(16) short lq[64 * 128];  // Q tile bf16, swizzled
  __shared__ __align__(16) short lp[64 * 256];  // P tile bf16, swizzled

  const float* __restrict__ Qb = Q + ((size_t)b * N_SEQ + n0) * D_HEAD;
  const short* __restrict__ kpb = kp + (size_t)b * (KP_DIM * D_HEAD);
  const short* __restrict__ vptb = vpt + (size_t)b * (KP_DIM * D_HEAD);

  // stage Q tile [64][128] f32 -> bf16 LDS
#pragma unroll
  for (int it = 0; it < 8; ++it) {
    int id = t + it * 256;
    int row = id >> 5, c4 = id & 31;
    f32x4 qv = *(const f32x4*)(Qb + (size_t)row * D_HEAD + c4 * 4);
    s16x4 h = {f2bf(qv[0]), f2bf(qv[1]), f2bf(qv[2]), f2bf(qv[3])};
    *(s16x4*)(&lq[row * 128 + ((c4 * 4) ^ ((row & 7) << 3))]) = h;
  }
  __syncthreads();

  // scores: A = Q rows [w*16, w*16+16), B = KP^T; acc over 16 col-tiles
  f32x4 accs[16];
#pragma unroll
  for (int i = 0; i < 16; ++i) accs[i] = (f32x4){0.f, 0.f, 0.f, 0.f};
#pragma unroll
  for (int ks = 0; ks < 4; ++ks) {
    int row = w * 16 + l15;
    bf16x8 a = *(const bf16x8*)(&lq[row * 128 + ((ks * 32 + l4 * 8) ^ ((row & 7) << 3))]);
#pragma unroll
    for (int nt = 0; nt < 16; ++nt) {
      bf16x8 bb = *(const bf16x8*)(&kpb[(size_t)(nt * 16 + l15) * D_HEAD + ks * 32 + l4 * 8]);
      accs[nt] = __builtin_amdgcn_mfma_f32_16x16x32_bf16(a, bb, accs[nt], 0, 0, 0);
    }
  }

  // softmax over 256 cols (16 nt-tiles x 16 lanes in group), rows = l4*4+r
  const float scale = 0.08838834764831845f;  // 1/sqrt(128)
#pragma unroll
  for (int r = 0; r < 4; ++r) {
    float m = -1e30f;
#pragma unroll
    for (int nt = 0; nt < 16; ++nt) {
      float v = accs[nt][r] * scale;
      accs[nt][r] = v;
      m = fmaxf(m, v);
    }
    m = fmaxf(m, __shfl_xor(m, 1));
    m = fmaxf(m, __shfl_xor(m, 2));
    m = fmaxf(m, __shfl_xor(m, 4));
    m = fmaxf(m, __shfl_xor(m, 8));
    float sum = 0.f;
#pragma unroll
    for (int nt = 0; nt < 16; ++nt) {
      float e = __expf(accs[nt][r] - m);
      accs[nt][r] = e;
      sum += e;
    }
    sum += __shfl_xor(sum, 1);
    sum += __shfl_xor(sum, 2);
    sum += __shfl_xor(sum, 4);
    sum += __shfl_xor(sum, 8);
    float inv = 1.0f / sum;
    int row = w * 16 + l4 * 4 + r;
#pragma unroll
    for (int nt = 0; nt < 16; ++nt) {
      int col = nt * 16 + l15;
      lp[row * 256 + (col ^ ((row & 7) << 3))] = f2bf(accs[nt][r] * inv);
    }
  }
  __syncthreads();

  // out = P @ VP : A = P rows, B[k][d] = VPT[d][k]
  f32x4 acco[8];
#pragma unroll
  for (int i = 0; i < 8; ++i) acco[i] = (f32x4){0.f, 0.f, 0.f, 0.f};
#pragma unroll
  for (int ks = 0; ks < 8; ++ks) {
    int row = w * 16 + l15;
    bf16x8 a = *(const bf16x8*)(&lp[row * 256 + ((ks * 32 + l4 * 8) ^ ((row & 7) << 3))]);
#pragma unroll
    for (int nt = 0; nt < 8; ++nt) {
      bf16x8 bb = *(const bf16x8*)(&vptb[(size_t)(nt * 16 + l15) * KP_DIM + ks * 32 + l4 * 8]);
      acco[nt] = __builtin_amdgcn_mfma_f32_16x16x32_bf16(a, bb, acco[nt], 0, 0, 0);
    }
  }
  float* __restrict__ ob = out + ((size_t)b * N_SEQ + n0 + w * 16) * D_HEAD;
#pragma unroll
  for (int nt = 0; nt < 8; ++nt)
#pragma unroll
    for (int r = 0; r < 4; ++r)
      ob[(size_t)(l4 * 4 + r) * D_HEAD + nt * 16 + l15] = acco[nt][r];
}

// ---------------------------------------------------------------------------
extern "C" void kernel_launch(void* const* d_in, const int* in_sizes, int n_in,
                              void* d_out, int out_size, void* d_ws, size_t ws_size,
                              hipStream_t stream) {
  const float* Q  = (const float*)d_in[0];
  const float* K  = (const float*)d_in[1];
  const float* V  = (const float*)d_in[2];
  const float* EW = (const float*)d_in[3];
  const float* Eb = (const float*)d_in[4];
  const float* FW = (const float*)d_in[5];
  const float* Fb = (const float*)d_in[6];
  float* out = (float*)d_out;

  // partials (33.5 MB) live in d_out-as-scratch; kp/vpt bf16 in ws (4.2 MB)
  float* pws = (float*)d_out;
  short* kpb = (short*)d_ws;
  short* vpt = (short*)((char*)d_ws + (size_t)32 * KP_DIM * D_HEAD * 2);

  proj_partial_kernel<<<dim3(4, 2, 32), dim3(512), 0, stream>>>(K, V, EW, FW, pws);
  reduce_bias_kernel<<<dim3(64), dim3(256), 0, stream>>>(pws, Eb, Fb, kpb, vpt);
  attn_kernel<<<dim3(64, 32), dim3(256), 0, stream>>>(Q, kpb, vpt, out);
}

// Round 2
// 177.161 us; speedup vs baseline: 1.4746x; 1.4746x over previous
//
#include <hip/hip_runtime.h>
#include <cstdint>
#include <cstddef>

#define N_SEQ 4096
#define D_HEAD 128
#define KP_DIM 256

typedef __attribute__((ext_vector_type(4))) float f32x4;
typedef __attribute__((ext_vector_type(8))) short bf16x8;
typedef __attribute__((ext_vector_type(4))) short s16x4;

static __device__ __forceinline__ short f2bf(float f) {
  uint32_t u = __builtin_bit_cast(uint32_t, f);
  u += 0x7FFFu + ((u >> 16) & 1u);
  return (short)(u >> 16);
}

static __device__ __forceinline__ int swz8(int r) { return (r ^ (r >> 2)) & 7; }

// Stage a [128 rows][256B] tile into 32KB of LDS with chunk-level XOR swizzle.
// LDS dest is linear (global_load_lds writes base + lane*16); the involution
// (chunk ^ (row&7)) is applied to the SOURCE address here and to the ds_read
// address in read_frag() below.
static __device__ __forceinline__ void stage_tile_swz(
    short* lds, const char* src, int rowStrideBytes, int w, int lane) {
#pragma unroll
  for (int i = 0; i < 8; ++i) {
    int cb = w * 8 + i;            // 1KB block, 0..31
    int g = cb * 64 + lane;        // 16B chunk id, 0..2047
    int row = g >> 4;              // 0..127
    int c = g & 15;
    const char* gp = src + (size_t)row * rowStrideBytes + ((c ^ (row & 7)) << 4);
    __builtin_amdgcn_global_load_lds(
        (const __attribute__((address_space(1))) void*)gp,
        (__attribute__((address_space(3))) void*)(lds + (size_t)cb * 512),
        16, 0, 0);
  }
}

static __device__ __forceinline__ bf16x8 read_frag(const short* lds, int row, int chunk) {
  return *(const bf16x8*)(&lds[row * 128 + ((chunk ^ (row & 7)) << 3)]);
}

// ---------------------------------------------------------------------------
// Stage 1: partial projections. 1D grid 256 (XCD-swizzled), 512 thr.
// pws[b][p][s][k(256)][d(128)] = sum_{n in chunk s} W[k,n] * X[b,n,d]
// ---------------------------------------------------------------------------
__global__ __launch_bounds__(512) void proj_partial_kernel(
    const float* __restrict__ Kin, const float* __restrict__ Vin,
    const float* __restrict__ EW, const float* __restrict__ FW,
    float* __restrict__ pws) {
  // bijective XCD swizzle: each XCD owns one (p,s) pair => 1MB of W in its L2
  const int bid = blockIdx.x;                 // 0..255
  const int wk = (bid & 7) * 32 + (bid >> 3);
  const int b = wk & 31;
  const int ps = wk >> 5;                     // 0..7
  const int s = ps & 3;
  const int p = ps >> 2;

  const float* __restrict__ X = (p == 0 ? Kin : Vin) + (size_t)b * (N_SEQ * D_HEAD);
  const float* __restrict__ W = (p == 0 ? EW : FW);
  float* __restrict__ outp = pws + ((((size_t)b * 2 + p) * 4) + s) * (KP_DIM * D_HEAD);

  __shared__ __align__(16) short lw[KP_DIM * 64];
  __shared__ __align__(16) short xt[D_HEAD * 64];

  const int t = threadIdx.x;
  const int lane = t & 63;
  const int w = t >> 6;
  const int wm = (w >> 1) * 64;
  const int wn = (w & 1) * 64;
  const int l15 = lane & 15;
  const int l4 = lane >> 4;

  f32x4 acc[4][4];
#pragma unroll
  for (int i = 0; i < 4; ++i)
#pragma unroll
    for (int j = 0; j < 4; ++j) acc[i][j] = (f32x4){0.f, 0.f, 0.f, 0.f};

  const int n0 = s * 1024;
  const int dq = t & 31;
  const int nq = t >> 5;

  for (int nb = 0; nb < 1024; nb += 64) {
    const int nc = n0 + nb;
#pragma unroll
    for (int it = 0; it < 8; ++it) {
      int id = t + it * 512;
      int kr = id >> 4, f4 = id & 15;
      f32x4 wv = *(const f32x4*)(W + (size_t)kr * N_SEQ + nc + f4 * 4);
      s16x4 h = {f2bf(wv[0]), f2bf(wv[1]), f2bf(wv[2]), f2bf(wv[3])};
      *(s16x4*)(&lw[kr * 64 + ((f4 * 4) ^ (swz8(kr) << 3))]) = h;
    }
    {
      f32x4 x0 = *(const f32x4*)(X + (size_t)(nc + nq * 4 + 0) * D_HEAD + dq * 4);
      f32x4 x1 = *(const f32x4*)(X + (size_t)(nc + nq * 4 + 1) * D_HEAD + dq * 4);
      f32x4 x2 = *(const f32x4*)(X + (size_t)(nc + nq * 4 + 2) * D_HEAD + dq * 4);
      f32x4 x3 = *(const f32x4*)(X + (size_t)(nc + nq * 4 + 3) * D_HEAD + dq * 4);
#pragma unroll
      for (int i = 0; i < 4; ++i) {
        int row = dq * 4 + i;
        s16x4 h = {f2bf(x0[i]), f2bf(x1[i]), f2bf(x2[i]), f2bf(x3[i])};
        *(s16x4*)(&xt[row * 64 + ((nq * 4) ^ (swz8(row) << 3))]) = h;
      }
    }
    __syncthreads();
#pragma unroll
    for (int ks2 = 0; ks2 < 2; ++ks2) {
      const int col0 = ks2 * 32 + l4 * 8;
      bf16x8 a[4], bb[4];
#pragma unroll
      for (int mt = 0; mt < 4; ++mt) {
        int row = wm + mt * 16 + l15;
        a[mt] = *(const bf16x8*)(&lw[row * 64 + (col0 ^ (swz8(row) << 3))]);
      }
#pragma unroll
      for (int nt = 0; nt < 4; ++nt) {
        int row = wn + nt * 16 + l15;
        bb[nt] = *(const bf16x8*)(&xt[row * 64 + (col0 ^ (swz8(row) << 3))]);
      }
#pragma unroll
      for (int mt = 0; mt < 4; ++mt)
#pragma unroll
        for (int nt = 0; nt < 4; ++nt)
          acc[mt][nt] = __builtin_amdgcn_mfma_f32_16x16x32_bf16(a[mt], bb[nt], acc[mt][nt], 0, 0, 0);
    }
    __syncthreads();
  }
#pragma unroll
  for (int mt = 0; mt < 4; ++mt)
#pragma unroll
    for (int nt = 0; nt < 4; ++nt)
#pragma unroll
      for (int r = 0; r < 4; ++r) {
        int kk = wm + mt * 16 + l4 * 4 + r;
        int dd = wn + nt * 16 + l15;
        outp[kk * D_HEAD + dd] = acc[mt][nt][r];
      }
}

// ---------------------------------------------------------------------------
// Stage 1b: reduce 4 partials + bias -> kp[b][k][d] bf16, vpt[b][d][k] bf16
// ---------------------------------------------------------------------------
__global__ __launch_bounds__(256) void reduce_bias_kernel(
    const float* __restrict__ pws, const float* __restrict__ Eb,
    const float* __restrict__ Fb, short* __restrict__ kp, short* __restrict__ vpt) {
  const int p = blockIdx.x & 1;
  const int b = blockIdx.x >> 1;
  const float* __restrict__ base = pws + (((size_t)b * 2 + p) * 4) * (KP_DIM * D_HEAD);
  const float* __restrict__ bias = (p == 0) ? Eb : Fb;
  const int t = threadIdx.x;
  __shared__ short tile[KP_DIM * D_HEAD];
  if (p == 0) {
    for (int i = t; i < KP_DIM * D_HEAD; i += 256) {
      int k = i >> 7;
      float v = base[i] + base[i + 32768] + base[i + 65536] + base[i + 98304] + bias[k];
      kp[(size_t)b * (KP_DIM * D_HEAD) + i] = f2bf(v);
    }
  } else {
    for (int i = t; i < KP_DIM * D_HEAD; i += 256) {
      int k = i >> 7, d = i & 127;
      float v = base[i] + base[i + 32768] + base[i + 65536] + base[i + 98304] + bias[k];
      tile[k * D_HEAD + (d ^ ((k & 15) << 3))] = f2bf(v);
    }
    __syncthreads();
    for (int i = t; i < KP_DIM * D_HEAD; i += 256) {
      int d = i >> 8, k = i & 255;
      vpt[(size_t)b * (KP_DIM * D_HEAD) + i] = tile[k * D_HEAD + (d ^ ((k & 15) << 3))];
    }
  }
}

// ---------------------------------------------------------------------------
// Stage 2: scores = Q @ KP^T * scale; softmax over k; out = P @ VP
// 1D grid 2048 (XCD-swizzled: each XCD owns 4 batches), 256 thr (4 waves).
// kp/vpt staged into one reused 32KB LDS buffer in halves via global_load_lds.
// ---------------------------------------------------------------------------
__global__ __launch_bounds__(256) void attn_kernel(
    const float* __restrict__ Q, const short* __restrict__ kp,
    const short* __restrict__ vpt, float* __restrict__ out) {
  const int bid = blockIdx.x;                  // 0..2047
  const int wk = (bid & 7) * 256 + (bid >> 3); // XCD x -> contiguous work chunk
  const int b = wk >> 6;
  const int tileI = wk & 63;
  const int n0 = tileI * 64;
  const int t = threadIdx.x;
  const int lane = t & 63;
  const int w = t >> 6;
  const int l15 = lane & 15, l4 = lane >> 4;

  __shared__ __align__(16) short lkv[128 * 128];  // 32KB: kp halves, then vpt halves
  __shared__ __align__(16) short lp[64 * 256];    // 32KB: P tile bf16, swizzled

  const short* __restrict__ kpb = kp + (size_t)b * (KP_DIM * D_HEAD);
  const short* __restrict__ vptb = vpt + (size_t)b * (KP_DIM * D_HEAD);

  // ---- issue kp half 0 staging, then load Q fragments (overlapped) ----
  stage_tile_swz(lkv, (const char*)kpb, 256, w, lane);

  bf16x8 qf[4];
  {
    const float* qrow = Q + ((size_t)b * N_SEQ + n0 + w * 16 + l15) * D_HEAD;
#pragma unroll
    for (int ks = 0; ks < 4; ++ks) {
      f32x4 q0 = *(const f32x4*)(qrow + ks * 32 + l4 * 8);
      f32x4 q1 = *(const f32x4*)(qrow + ks * 32 + l4 * 8 + 4);
      qf[ks] = (bf16x8){f2bf(q0[0]), f2bf(q0[1]), f2bf(q0[2]), f2bf(q0[3]),
                        f2bf(q1[0]), f2bf(q1[1]), f2bf(q1[2]), f2bf(q1[3])};
    }
  }
  asm volatile("s_waitcnt vmcnt(0)" ::: "memory");
  __syncthreads();

  // ---- scores ----
  f32x4 accs[16];
#pragma unroll
  for (int i = 0; i < 16; ++i) accs[i] = (f32x4){0.f, 0.f, 0.f, 0.f};

#pragma unroll
  for (int h = 0; h < 2; ++h) {
    if (h == 1) {
      __syncthreads();  // all waves done reading half 0
      stage_tile_swz(lkv, (const char*)kpb + 128 * 256, 256, w, lane);
      asm volatile("s_waitcnt vmcnt(0)" ::: "memory");
      __syncthreads();
    }
#pragma unroll
    for (int ks = 0; ks < 4; ++ks) {
#pragma unroll
      for (int ntl = 0; ntl < 8; ++ntl) {
        bf16x8 bb = read_frag(lkv, ntl * 16 + l15, ks * 4 + l4);
        accs[h * 8 + ntl] =
            __builtin_amdgcn_mfma_f32_16x16x32_bf16(qf[ks], bb, accs[h * 8 + ntl], 0, 0, 0);
      }
    }
  }

  // ---- softmax over 256 cols; rows = w*16 + l4*4 + r, col group = l15 ----
  const float scale = 0.08838834764831845f;  // 1/sqrt(128)
#pragma unroll
  for (int r = 0; r < 4; ++r) {
    float m = -1e30f;
#pragma unroll
    for (int nt = 0; nt < 16; ++nt) {
      float v = accs[nt][r] * scale;
      accs[nt][r] = v;
      m = fmaxf(m, v);
    }
    m = fmaxf(m, __shfl_xor(m, 1));
    m = fmaxf(m, __shfl_xor(m, 2));
    m = fmaxf(m, __shfl_xor(m, 4));
    m = fmaxf(m, __shfl_xor(m, 8));
    float sum = 0.f;
#pragma unroll
    for (int nt = 0; nt < 16; ++nt) {
      float e = __expf(accs[nt][r] - m);
      accs[nt][r] = e;
      sum += e;
    }
    sum += __shfl_xor(sum, 1);
    sum += __shfl_xor(sum, 2);
    sum += __shfl_xor(sum, 4);
    sum += __shfl_xor(sum, 8);
    float inv = 1.0f / sum;
    int row = w * 16 + l4 * 4 + r;
#pragma unroll
    for (int nt = 0; nt < 16; ++nt) {
      int col = nt * 16 + l15;
      lp[row * 256 + (col ^ ((row & 7) << 3))] = f2bf(accs[nt][r] * inv);
    }
  }

  // ---- out = P @ VP, vpt staged in k-halves into lkv ----
  f32x4 acco[8];
#pragma unroll
  for (int i = 0; i < 8; ++i) acco[i] = (f32x4){0.f, 0.f, 0.f, 0.f};

#pragma unroll
  for (int h = 0; h < 2; ++h) {
    __syncthreads();  // waves done reading lkv (and lp writes drained on h==0)
    stage_tile_swz(lkv, (const char*)vptb + h * 256, 512, w, lane);
    asm volatile("s_waitcnt vmcnt(0)" ::: "memory");
    __syncthreads();
#pragma unroll
    for (int ksl = 0; ksl < 4; ++ksl) {
      int kk = h * 128 + ksl * 32 + l4 * 8;
      int prow = w * 16 + l15;
      bf16x8 ap = *(const bf16x8*)(&lp[prow * 256 + (kk ^ ((prow & 7) << 3))]);
#pragma unroll
      for (int ntv = 0; ntv < 8; ++ntv) {
        bf16x8 bv = read_frag(lkv, ntv * 16 + l15, ksl * 4 + l4);
        acco[ntv] = __builtin_amdgcn_mfma_f32_16x16x32_bf16(ap, bv, acco[ntv], 0, 0, 0);
      }
    }
  }

  float* __restrict__ ob = out + ((size_t)b * N_SEQ + n0 + w * 16) * D_HEAD;
#pragma unroll
  for (int ntv = 0; ntv < 8; ++ntv)
#pragma unroll
    for (int r = 0; r < 4; ++r)
      ob[(size_t)(l4 * 4 + r) * D_HEAD + ntv * 16 + l15] = acco[ntv][r];
}

// ---------------------------------------------------------------------------
extern "C" void kernel_launch(void* const* d_in, const int* in_sizes, int n_in,
                              void* d_out, int out_size, void* d_ws, size_t ws_size,
                              hipStream_t stream) {
  const float* Q  = (const float*)d_in[0];
  const float* K  = (const float*)d_in[1];
  const float* V  = (const float*)d_in[2];
  const float* EW = (const float*)d_in[3];
  const float* Eb = (const float*)d_in[4];
  const float* FW = (const float*)d_in[5];
  const float* Fb = (const float*)d_in[6];
  float* out = (float*)d_out;

  float* pws = (float*)d_out;  // 33.5MB partials scratch inside d_out
  short* kpb = (short*)d_ws;
  short* vpt = (short*)((char*)d_ws + (size_t)32 * KP_DIM * D_HEAD * 2);

  proj_partial_kernel<<<dim3(256), dim3(512), 0, stream>>>(K, V, EW, FW, pws);
  reduce_bias_kernel<<<dim3(64), dim3(256), 0, stream>>>(pws, Eb, Fb, kpb, vpt);
  attn_kernel<<<dim3(2048), dim3(256), 0, stream>>>(Q, kpb, vpt, out);
}

// Round 3
// 139.254 us; speedup vs baseline: 1.8759x; 1.2722x over previous
//
#include <hip/hip_runtime.h>
#include <cstdint>
#include <cstddef>

#define N_SEQ 4096
#define D_HEAD 128
#define KP_DIM 256

typedef __attribute__((ext_vector_type(4))) float f32x4;
typedef __attribute__((ext_vector_type(8))) short bf16x8;
typedef __attribute__((ext_vector_type(4))) short s16x4;
typedef __attribute__((ext_vector_type(2))) unsigned int u32x2;

static __device__ __forceinline__ short f2bf(float f) {
  uint32_t u = __builtin_bit_cast(uint32_t, f);
  u += 0x7FFFu + ((u >> 16) & 1u);
  return (short)(u >> 16);
}

// packed f32x2 -> bf16x2 (RNE), 1 VALU inst for 2 elements
static __device__ __forceinline__ unsigned int cvtpk(float a, float b) {
  unsigned int r;
  asm("v_cvt_pk_bf16_f32 %0, %1, %2" : "=v"(r) : "v"(a), "v"(b));
  return r;
}

static __device__ __forceinline__ int swz8(int r) { return (r ^ (r >> 2)) & 7; }

// Stage a [128 rows][256B] tile into 32KB of LDS with chunk-level XOR swizzle
// (linear LDS dest for global_load_lds; involution applied to SOURCE address
// here and to the ds_read address in read_frag).
static __device__ __forceinline__ void stage_tile_swz(
    short* lds, const char* src, int rowStrideBytes, int w, int lane) {
#pragma unroll
  for (int i = 0; i < 8; ++i) {
    int cb = w * 8 + i;
    int g = cb * 64 + lane;
    int row = g >> 4;
    int c = g & 15;
    const char* gp = src + (size_t)row * rowStrideBytes + ((c ^ (row & 7)) << 4);
    __builtin_amdgcn_global_load_lds(
        (const __attribute__((address_space(1))) void*)gp,
        (__attribute__((address_space(3))) void*)(lds + (size_t)cb * 512),
        16, 0, 0);
  }
}

static __device__ __forceinline__ bf16x8 read_frag(const short* lds, int row, int chunk) {
  return *(const bf16x8*)(&lds[row * 128 + ((chunk ^ (row & 7)) << 3)]);
}

// ---------------------------------------------------------------------------
// Stage 1: partial projections. grid 512 (XCD-chunked), 256 thr (4 waves 2x2).
// Block = (b, p, m, s): out tile k in [m*128, m*128+128), all 128 d,
// K-range n in [s*1024, s*1024+1024). Double-buffered LDS, reg-staged loads,
// cvt_pk f32->bf16. pws[b][p][s][k 256][d 128] f32 partials (in d_out).
// ---------------------------------------------------------------------------
__global__ __launch_bounds__(256) void proj_partial_kernel(
    const float* __restrict__ Kin, const float* __restrict__ Vin,
    const float* __restrict__ EW, const float* __restrict__ FW,
    float* __restrict__ pws) {
  const int bid = blockIdx.x;                 // 0..511
  const int wk = (bid & 7) * 64 + (bid >> 3); // chunked: XCD x owns wk [64x,64x+64)
  const int m = wk & 1;                       // m-pairs adjacent -> same XCD
  const int b = (wk >> 1) & 31;
  const int p = (wk >> 6) & 1;                // per XCD-chunk: one p, one s
  const int s = wk >> 7;

  const float* __restrict__ X = (p == 0 ? Kin : Vin) + (size_t)b * (N_SEQ * D_HEAD);
  const float* __restrict__ W = (p == 0 ? EW : FW) + (size_t)m * 128 * N_SEQ;
  float* __restrict__ outp = pws + ((((size_t)b * 2 + p) * 4) + s) * (KP_DIM * D_HEAD)
                             + m * 128 * D_HEAD;

  __shared__ __align__(16) short lw[2][128 * 64];  // W tile [128 k][64 n]
  __shared__ __align__(16) short xt[2][128 * 64];  // X^T tile [128 d][64 n]

  const int t = threadIdx.x;
  const int lane = t & 63;
  const int w = t >> 6;
  const int wm = (w >> 1) * 64;
  const int wn = (w & 1) * 64;
  const int l15 = lane & 15;
  const int l4 = lane >> 4;
  const int dq = t & 31;   // d-quad for X staging
  const int ng0 = t >> 5;  // n-group base (0..7)

  const int n0 = s * 1024;

  f32x4 acc[4][4];
#pragma unroll
  for (int i = 0; i < 4; ++i)
#pragma unroll
    for (int j = 0; j < 4; ++j) acc[i][j] = (f32x4){0.f, 0.f, 0.f, 0.f};

  f32x4 wreg[8], xreg[8];

  // prologue: issue loads for iter 0
#pragma unroll
  for (int i = 0; i < 8; ++i) {
    int id = t + i * 256;
    wreg[i] = *(const f32x4*)(W + (size_t)(id >> 4) * N_SEQ + n0 + (id & 15) * 4);
  }
#pragma unroll
  for (int r = 0; r < 2; ++r)
#pragma unroll
    for (int i = 0; i < 4; ++i)
      xreg[r * 4 + i] =
          *(const f32x4*)(X + (size_t)(n0 + (ng0 + r * 8) * 4 + i) * D_HEAD + dq * 4);

#pragma unroll 2
  for (int it = 0; it < 16; ++it) {
    const int cur = it & 1;
    asm volatile("s_waitcnt vmcnt(0)" ::: "memory");
    // ---- convert + ds_write W tile ----
#pragma unroll
    for (int i = 0; i < 8; ++i) {
      int id = t + i * 256;
      int row = id >> 4, q = id & 15;
      u32x2 hv = {cvtpk(wreg[i][0], wreg[i][1]), cvtpk(wreg[i][2], wreg[i][3])};
      *(u32x2*)(&lw[cur][row * 64 + ((q * 4) ^ (swz8(row) << 3))]) = hv;
    }
    // ---- convert + ds_write X^T tile (transpose in registers) ----
#pragma unroll
    for (int r = 0; r < 2; ++r) {
      int ng = ng0 + r * 8;
#pragma unroll
      for (int j = 0; j < 4; ++j) {
        int drow = dq * 4 + j;
        u32x2 hv = {cvtpk(xreg[r * 4 + 0][j], xreg[r * 4 + 1][j]),
                    cvtpk(xreg[r * 4 + 2][j], xreg[r * 4 + 3][j])};
        *(u32x2*)(&xt[cur][drow * 64 + ((ng * 4) ^ (swz8(drow) << 3))]) = hv;
      }
    }
    __syncthreads();
    // ---- issue loads for iter t+1 (fly under MFMA below) ----
    if (it < 15) {
      const int nc = n0 + (it + 1) * 64;
#pragma unroll
      for (int i = 0; i < 8; ++i) {
        int id = t + i * 256;
        wreg[i] = *(const f32x4*)(W + (size_t)(id >> 4) * N_SEQ + nc + (id & 15) * 4);
      }
#pragma unroll
      for (int r = 0; r < 2; ++r)
#pragma unroll
        for (int i = 0; i < 4; ++i)
          xreg[r * 4 + i] =
              *(const f32x4*)(X + (size_t)(nc + (ng0 + r * 8) * 4 + i) * D_HEAD + dq * 4);
    }
    // ---- compute on buf[cur] ----
#pragma unroll
    for (int ks2 = 0; ks2 < 2; ++ks2) {
      const int col0 = ks2 * 32 + l4 * 8;
      bf16x8 a[4], bb[4];
#pragma unroll
      for (int mt = 0; mt < 4; ++mt) {
        int row = wm + mt * 16 + l15;
        a[mt] = *(const bf16x8*)(&lw[cur][row * 64 + (col0 ^ (swz8(row) << 3))]);
      }
#pragma unroll
      for (int nt = 0; nt < 4; ++nt) {
        int row = wn + nt * 16 + l15;
        bb[nt] = *(const bf16x8*)(&xt[cur][row * 64 + (col0 ^ (swz8(row) << 3))]);
      }
#pragma unroll
      for (int mt = 0; mt < 4; ++mt)
#pragma unroll
        for (int nt = 0; nt < 4; ++nt)
          acc[mt][nt] = __builtin_amdgcn_mfma_f32_16x16x32_bf16(a[mt], bb[nt], acc[mt][nt], 0, 0, 0);
    }
  }
  // ---- write f32 partials ----
#pragma unroll
  for (int mt = 0; mt < 4; ++mt)
#pragma unroll
    for (int nt = 0; nt < 4; ++nt)
#pragma unroll
      for (int r = 0; r < 4; ++r) {
        int kk = wm + mt * 16 + l4 * 4 + r;
        int dd = wn + nt * 16 + l15;
        outp[kk * D_HEAD + dd] = acc[mt][nt][r];
      }
}

// ---------------------------------------------------------------------------
// Stage 1b: reduce 4 partials + bias -> kp[b][k][d] bf16, vpt[b][d][k] bf16
// ---------------------------------------------------------------------------
__global__ __launch_bounds__(256) void reduce_bias_kernel(
    const float* __restrict__ pws, const float* __restrict__ Eb,
    const float* __restrict__ Fb, short* __restrict__ kp, short* __restrict__ vpt) {
  const int p = blockIdx.x & 1;
  const int b = blockIdx.x >> 1;
  const float* __restrict__ base = pws + (((size_t)b * 2 + p) * 4) * (KP_DIM * D_HEAD);
  const float* __restrict__ bias = (p == 0) ? Eb : Fb;
  const int t = threadIdx.x;
  __shared__ short tile[KP_DIM * D_HEAD];
  if (p == 0) {
    for (int i = t; i < KP_DIM * D_HEAD; i += 256) {
      int k = i >> 7;
      float v = base[i] + base[i + 32768] + base[i + 65536] + base[i + 98304] + bias[k];
      kp[(size_t)b * (KP_DIM * D_HEAD) + i] = f2bf(v);
    }
  } else {
    for (int i = t; i < KP_DIM * D_HEAD; i += 256) {
      int k = i >> 7, d = i & 127;
      float v = base[i] + base[i + 32768] + base[i + 65536] + base[i + 98304] + bias[k];
      tile[k * D_HEAD + (d ^ ((k & 15) << 3))] = f2bf(v);
    }
    __syncthreads();
    for (int i = t; i < KP_DIM * D_HEAD; i += 256) {
      int d = i >> 8, k = i & 255;
      vpt[(size_t)b * (KP_DIM * D_HEAD) + i] = tile[k * D_HEAD + (d ^ ((k & 15) << 3))];
    }
  }
}

// ---------------------------------------------------------------------------
// Stage 2: scores = Q @ KP^T * scale; softmax over k; out = P @ VP
// 1D grid 2048 (XCD-swizzled), 256 thr (4 waves); kp/vpt staged via
// global_load_lds into one reused 32KB LDS buffer.
// ---------------------------------------------------------------------------
__global__ __launch_bounds__(256) void attn_kernel(
    const float* __restrict__ Q, const short* __restrict__ kp,
    const short* __restrict__ vpt, float* __restrict__ out) {
  const int bid = blockIdx.x;
  const int wk = (bid & 7) * 256 + (bid >> 3);
  const int b = wk >> 6;
  const int tileI = wk & 63;
  const int n0 = tileI * 64;
  const int t = threadIdx.x;
  const int lane = t & 63;
  const int w = t >> 6;
  const int l15 = lane & 15, l4 = lane >> 4;

  __shared__ __align__(16) short lkv[128 * 128];
  __shared__ __align__(16) short lp[64 * 256];

  const short* __restrict__ kpb = kp + (size_t)b * (KP_DIM * D_HEAD);
  const short* __restrict__ vptb = vpt + (size_t)b * (KP_DIM * D_HEAD);

  stage_tile_swz(lkv, (const char*)kpb, 256, w, lane);

  bf16x8 qf[4];
  {
    const float* qrow = Q + ((size_t)b * N_SEQ + n0 + w * 16 + l15) * D_HEAD;
#pragma unroll
    for (int ks = 0; ks < 4; ++ks) {
      f32x4 q0 = *(const f32x4*)(qrow + ks * 32 + l4 * 8);
      f32x4 q1 = *(const f32x4*)(qrow + ks * 32 + l4 * 8 + 4);
      qf[ks] = (bf16x8){f2bf(q0[0]), f2bf(q0[1]), f2bf(q0[2]), f2bf(q0[3]),
                        f2bf(q1[0]), f2bf(q1[1]), f2bf(q1[2]), f2bf(q1[3])};
    }
  }
  asm volatile("s_waitcnt vmcnt(0)" ::: "memory");
  __syncthreads();

  f32x4 accs[16];
#pragma unroll
  for (int i = 0; i < 16; ++i) accs[i] = (f32x4){0.f, 0.f, 0.f, 0.f};

#pragma unroll
  for (int h = 0; h < 2; ++h) {
    if (h == 1) {
      __syncthreads();
      stage_tile_swz(lkv, (const char*)kpb + 128 * 256, 256, w, lane);
      asm volatile("s_waitcnt vmcnt(0)" ::: "memory");
      __syncthreads();
    }
#pragma unroll
    for (int ks = 0; ks < 4; ++ks) {
#pragma unroll
      for (int ntl = 0; ntl < 8; ++ntl) {
        bf16x8 bb = read_frag(lkv, ntl * 16 + l15, ks * 4 + l4);
        accs[h * 8 + ntl] =
            __builtin_amdgcn_mfma_f32_16x16x32_bf16(qf[ks], bb, accs[h * 8 + ntl], 0, 0, 0);
      }
    }
  }

  const float scale = 0.08838834764831845f;
#pragma unroll
  for (int r = 0; r < 4; ++r) {
    float m = -1e30f;
#pragma unroll
    for (int nt = 0; nt < 16; ++nt) {
      float v = accs[nt][r] * scale;
      accs[nt][r] = v;
      m = fmaxf(m, v);
    }
    m = fmaxf(m, __shfl_xor(m, 1));
    m = fmaxf(m, __shfl_xor(m, 2));
    m = fmaxf(m, __shfl_xor(m, 4));
    m = fmaxf(m, __shfl_xor(m, 8));
    float sum = 0.f;
#pragma unroll
    for (int nt = 0; nt < 16; ++nt) {
      float e = __expf(accs[nt][r] - m);
      accs[nt][r] = e;
      sum += e;
    }
    sum += __shfl_xor(sum, 1);
    sum += __shfl_xor(sum, 2);
    sum += __shfl_xor(sum, 4);
    sum += __shfl_xor(sum, 8);
    float inv = 1.0f / sum;
    int row = w * 16 + l4 * 4 + r;
#pragma unroll
    for (int nt = 0; nt < 16; ++nt) {
      int col = nt * 16 + l15;
      lp[row * 256 + (col ^ ((row & 7) << 3))] = f2bf(accs[nt][r] * inv);
    }
  }

  f32x4 acco[8];
#pragma unroll
  for (int i = 0; i < 8; ++i) acco[i] = (f32x4){0.f, 0.f, 0.f, 0.f};

#pragma unroll
  for (int h = 0; h < 2; ++h) {
    __syncthreads();
    stage_tile_swz(lkv, (const char*)vptb + h * 256, 512, w, lane);
    asm volatile("s_waitcnt vmcnt(0)" ::: "memory");
    __syncthreads();
#pragma unroll
    for (int ksl = 0; ksl < 4; ++ksl) {
      int kk = h * 128 + ksl * 32 + l4 * 8;
      int prow = w * 16 + l15;
      bf16x8 ap = *(const bf16x8*)(&lp[prow * 256 + (kk ^ ((prow & 7) << 3))]);
#pragma unroll
      for (int ntv = 0; ntv < 8; ++ntv) {
        bf16x8 bv = read_frag(lkv, ntv * 16 + l15, ksl * 4 + l4);
        acco[ntv] = __builtin_amdgcn_mfma_f32_16x16x32_bf16(ap, bv, acco[ntv], 0, 0, 0);
      }
    }
  }

  float* __restrict__ ob = out + ((size_t)b * N_SEQ + n0 + w * 16) * D_HEAD;
#pragma unroll
  for (int ntv = 0; ntv < 8; ++ntv)
#pragma unroll
    for (int r = 0; r < 4; ++r)
      ob[(size_t)(l4 * 4 + r) * D_HEAD + ntv * 16 + l15] = acco[ntv][r];
}

// ---------------------------------------------------------------------------
extern "C" void kernel_launch(void* const* d_in, const int* in_sizes, int n_in,
                              void* d_out, int out_size, void* d_ws, size_t ws_size,
                              hipStream_t stream) {
  const float* Q  = (const float*)d_in[0];
  const float* K  = (const float*)d_in[1];
  const float* V  = (const float*)d_in[2];
  const float* EW = (const float*)d_in[3];
  const float* Eb = (const float*)d_in[4];
  const float* FW = (const float*)d_in[5];
  const float* Fb = (const float*)d_in[6];
  float* out = (float*)d_out;

  float* pws = (float*)d_out;  // 33.5MB f32 partials scratch inside d_out
  short* kpb = (short*)d_ws;
  short* vpt = (short*)((char*)d_ws + (size_t)32 * KP_DIM * D_HEAD * 2);

  proj_partial_kernel<<<dim3(512), dim3(256), 0, stream>>>(K, V, EW, FW, pws);
  reduce_bias_kernel<<<dim3(64), dim3(256), 0, stream>>>(pws, Eb, Fb, kpb, vpt);
  attn_kernel<<<dim3(2048), dim3(256), 0, stream>>>(Q, kpb, vpt, out);
}